// Round 6
// baseline (140.995 us; speedup 1.0000x reference)
//
#include <hip/hip_runtime.h>
#include <stdint.h>

#define D 4096
#define RANK 8
#define ALPHA 1.5f
#define BETA 0.5f
#define SUM_TIMESTEPS 28000
#define K_TOP 64
#define NBINS 1024

typedef float f32x4 __attribute__((ext_vector_type(4)));

// ws layout (bytes):
//   [0, 256)          : u32 hdr[]: [0]=maxbits1 [1]=maxbits2 [4]=flag
//   [256, 256+8K)     : u32 gcnt[2][NBINS]
//   [8448, 8448+16K)  : u64 gsum[2][NBINS]   (fixed-point, deterministic)
#define WS_HCNT_OFF 256
#define WS_HSUM_OFF (256 + 2 * NBINS * 4)
// words to zero: 64 + 2048 + 4096 = 6208
#define WS_ZERO_WORDS 6208

// fixed-point scale: 2^38 / max  (sum of 16.7M maximal values still < 2^62)
#define FIX_NUM 2.74877906944e11f
#define FIX_INV 3.637978807091713e-12   // 2^-38

__global__ __launch_bounds__(1024) void k_init(unsigned* __restrict__ w) {
    for (int i = threadIdx.x; i < WS_ZERO_WORDS; i += 1024) w[i] = 0u;
}

__device__ __forceinline__ float dot4v(f32x4 a, f32x4 b) {
    return fmaf(a.x, b.x, fmaf(a.y, b.y, fmaf(a.z, b.z, a.w * b.w)));
}

// ---------------------------------------------------------------------------
// Pass 1: global max of |wa@wb| per matrix (bitwise atomicMax: deterministic).
// ---------------------------------------------------------------------------
__global__ __launch_bounds__(256) void k_pass_max(
    const float* __restrict__ wa1, const float* __restrict__ wb1,
    const float* __restrict__ wa2, const float* __restrict__ wb2,
    unsigned* __restrict__ hdr) {
    const int tid = threadIdx.x;
    const int mat = blockIdx.y;
    const float* __restrict__ wa = mat ? wa2 : wa1;
    const float* __restrict__ wb = mat ? wb2 : wb1;
    const int i0 = (blockIdx.x & 3) * 1024 + tid * 4;
    const int obase = (blockIdx.x >> 2) * 64;

    f32x4 wbv[RANK];
#pragma unroll
    for (int r = 0; r < RANK; ++r)
        wbv[r] = *(const f32x4*)(wb + r * D + i0);

    float vmax = 0.f;
#pragma unroll 4
    for (int oo = 0; oo < 64; ++oo) {
        const float* __restrict__ war = wa + (size_t)(obase + oo) * RANK;
        f32x4 s = {0.f, 0.f, 0.f, 0.f};
#pragma unroll
        for (int r = 0; r < RANK; ++r) {
            const float a = war[r];
            s.x = fmaf(a, wbv[r].x, s.x);
            s.y = fmaf(a, wbv[r].y, s.y);
            s.z = fmaf(a, wbv[r].z, s.z);
            s.w = fmaf(a, wbv[r].w, s.w);
        }
        vmax = fmaxf(vmax, fmaxf(fmaxf(fabsf(s.x), fabsf(s.y)),
                                 fmaxf(fabsf(s.z), fabsf(s.w))));
    }
    for (int off = 32; off; off >>= 1)
        vmax = fmaxf(vmax, __shfl_xor(vmax, off, 64));
    __shared__ float smax[4];
    const int wave = tid >> 6, lane = tid & 63;
    if (lane == 0) smax[wave] = vmax;
    __syncthreads();
    if (tid == 0) {
        float m = fmaxf(fmaxf(smax[0], smax[1]), fmaxf(smax[2], smax[3]));
        atomicMax(&hdr[mat], __float_as_uint(m));  // positive floats: bit order == value order
    }
}

// ---------------------------------------------------------------------------
// Pass 2: histogram all |elem| >= 0.5*max. Counts = u32; sums = u64 FIXED
// POINT (av * 2^38/max) -> integer atomics are order-independent, so the
// whole flag path is bit-deterministic across replays.
// ---------------------------------------------------------------------------
__global__ __launch_bounds__(256) void k_pass_hist(
    const float* __restrict__ wa1, const float* __restrict__ wb1,
    const float* __restrict__ wa2, const float* __restrict__ wb2,
    const unsigned* __restrict__ hdr,
    unsigned* __restrict__ gcnt, unsigned long long* __restrict__ gsum) {
    __shared__ unsigned lcnt[NBINS];
    __shared__ unsigned long long lsum[NBINS];
    const int tid = threadIdx.x;
    const int mat = blockIdx.y;
    for (int b = tid; b < NBINS; b += 256) { lcnt[b] = 0u; lsum[b] = 0ull; }
    __syncthreads();

    const float* __restrict__ wa = mat ? wa2 : wa1;
    const float* __restrict__ wb = mat ? wb2 : wb1;
    const float M = __uint_as_float(hdr[mat]);
    const float T = 0.5f * M;
    const float fix = FIX_NUM / M;
    const unsigned bitsT = __float_as_uint(T);
    const int i0 = (blockIdx.x & 3) * 1024 + tid * 4;
    const int obase = (blockIdx.x >> 2) * 64;

    f32x4 wbv[RANK];
#pragma unroll
    for (int r = 0; r < RANK; ++r)
        wbv[r] = *(const f32x4*)(wb + r * D + i0);

#pragma unroll 2
    for (int oo = 0; oo < 64; ++oo) {
        const float* __restrict__ war = wa + (size_t)(obase + oo) * RANK;
        f32x4 s = {0.f, 0.f, 0.f, 0.f};
#pragma unroll
        for (int r = 0; r < RANK; ++r) {
            const float a = war[r];
            s.x = fmaf(a, wbv[r].x, s.x);
            s.y = fmaf(a, wbv[r].y, s.y);
            s.z = fmaf(a, wbv[r].z, s.z);
            s.w = fmaf(a, wbv[r].w, s.w);
        }
        const float av[4] = {fabsf(s.x), fabsf(s.y), fabsf(s.z), fabsf(s.w)};
#pragma unroll
        for (int j = 0; j < 4; ++j) {
            if (av[j] >= T) {
                unsigned k = (__float_as_uint(av[j]) - bitsT) >> 13;
                if (k > NBINS - 1u) k = NBINS - 1u;
                atomicAdd(&lcnt[k], 1u);
                atomicAdd(&lsum[k], (unsigned long long)(av[j] * fix));
            }
        }
    }
    __syncthreads();
    unsigned* __restrict__ gc = gcnt + (size_t)mat * NBINS;
    unsigned long long* __restrict__ gs = gsum + (size_t)mat * NBINS;
    for (int b = tid; b < NBINS; b += 256) {
        unsigned c = lcnt[b];
        if (c) {
            atomicAdd(&gc[b], c);
            atomicAdd(&gs[b], lsum[b]);
        }
    }
}

// ---------------------------------------------------------------------------
// Pass 3: one block, 1024 threads; suffix-scan histogram (integer — exact),
// top-64 cutoff, flag. Fully deterministic.
// ---------------------------------------------------------------------------
__global__ __launch_bounds__(1024) void k_select(
    unsigned* __restrict__ hdr,
    const unsigned* __restrict__ gcnt, const unsigned long long* __restrict__ gsum,
    const int* __restrict__ tsp) {
    __shared__ unsigned sc[NBINS];
    __shared__ unsigned long long ss[NBINS];
    __shared__ float res[2];
    __shared__ int sB;
    const int b = threadIdx.x;

    for (int mat = 0; mat < 2; ++mat) {
        if (b == 0) sB = -1;
        const unsigned c0 = gcnt[(size_t)mat * NBINS + b];
        const unsigned long long s0 = gsum[(size_t)mat * NBINS + b];
        __syncthreads();           // previous iteration's readers done
        sc[b] = c0;
        ss[b] = s0;
        __syncthreads();
        // Hillis-Steele suffix scan (integer adds: exact, order-independent)
        for (int step = 1; step < NBINS; step <<= 1) {
            unsigned c2 = 0u; unsigned long long s2 = 0ull;
            if (b + step < NBINS) { c2 = sc[b + step]; s2 = ss[b + step]; }
            __syncthreads();
            sc[b] += c2;
            ss[b] += s2;
            __syncthreads();
        }
        if (sc[b] >= K_TOP && (b == NBINS - 1 || sc[b + 1] < K_TOP)) sB = b;
        __syncthreads();
        if (b == 0) {
            const float M = __uint_as_float(hdr[mat]);
            const double inv = (double)M * FIX_INV;  // decode: units -> value
            float total;
            if (sB < 0) {
                total = (float)((double)ss[0] * inv);
            } else {
                const int B = sB;
                const unsigned cAbove = (B + 1 < NBINS) ? sc[B + 1] : 0u;
                const unsigned long long sAbove = (B + 1 < NBINS) ? ss[B + 1] : 0ull;
                const unsigned cb = sc[B] - cAbove;
                const unsigned long long sb = ss[B] - sAbove;
                const unsigned need = K_TOP - cAbove;
                total = (float)((double)sAbove * inv)
                      + (float)((double)sb * inv) * ((float)need / (float)cb);
            }
            res[mat] = total;
        }
        __syncthreads();
    }
    if (b == 0) {
        const int tr = (*tsp) % SUM_TIMESTEPS;
        const float scale = fmodf(ALPHA * (float)tr / (float)SUM_TIMESTEPS + BETA, ALPHA);
        const float temp_ratio = res[0] / (res[1] * scale);  // AVG_RATIO = 1.0
        hdr[4] = (temp_ratio > 1.0f) ? 1u : 0u;              // 1 -> matrix1
    }
}

// ---------------------------------------------------------------------------
// Fused GEMM, wave-independent (round-4 structure, replay-proven): each wave
// owns 2 rows end-to-end — no LDS, no barrier, no inter-wave coupling.
//   phase 1: acc[2][8] = h_rows @ wb^T; xor-butterfly leaves full t in EVERY
//            lane.
//   phase 2: same wave streams its 2 output rows (nt stores).
// 1024 blocks (4/CU -> 16 waves/CU) for latency hiding.
// ---------------------------------------------------------------------------
__global__ __launch_bounds__(256) void k_fused(
    const float* __restrict__ h,
    const float* __restrict__ wa1, const float* __restrict__ wb1,
    const float* __restrict__ wa2, const float* __restrict__ wb2,
    const unsigned* __restrict__ hdr,
    float* __restrict__ out) {
    const int tid = threadIdx.x;
    const int wave = tid >> 6, lane = tid & 63;
    const unsigned flag = hdr[4];
    const float* __restrict__ wa = flag ? wa1 : wa2;
    const float* __restrict__ wb = flag ? wb1 : wb2;
    const size_t m0 = ((size_t)blockIdx.x * 4 + wave) * 2;

    float acc[2][RANK];
#pragma unroll
    for (int row = 0; row < 2; ++row)
#pragma unroll
        for (int r = 0; r < RANK; ++r) acc[row][r] = 0.f;

#pragma unroll 4
    for (int k = 0; k < 16; ++k) {
        const int i = k * 256 + lane * 4;
        f32x4 hv[2];
#pragma unroll
        for (int row = 0; row < 2; ++row)
            hv[row] = *(const f32x4*)(h + (m0 + row) * D + i);
        f32x4 wbv[RANK];
#pragma unroll
        for (int r = 0; r < RANK; ++r)
            wbv[r] = *(const f32x4*)(wb + r * D + i);
#pragma unroll
        for (int row = 0; row < 2; ++row)
#pragma unroll
            for (int r = 0; r < RANK; ++r)
                acc[row][r] = fmaf(hv[row].x, wbv[r].x,
                              fmaf(hv[row].y, wbv[r].y,
                              fmaf(hv[row].z, wbv[r].z,
                              fmaf(hv[row].w, wbv[r].w, acc[row][r]))));
    }
    // butterfly reduce over i: afterwards every lane holds t[row][r]
#pragma unroll
    for (int row = 0; row < 2; ++row)
#pragma unroll
        for (int r = 0; r < RANK; ++r)
#pragma unroll
            for (int off = 32; off; off >>= 1)
                acc[row][r] += __shfl_xor(acc[row][r], off, 64);

    // phase 2: out[m0..m0+1, :] = t @ wa^T, 256 cols per chunk
    for (int c = 0; c < 16; ++c) {
        const int o0 = c * 256 + lane * 4;
        f32x4 A[8];  // A[2j]: col (o0+j) r0..3, A[2j+1]: r4..7
#pragma unroll
        for (int j = 0; j < 8; ++j)
            A[j] = *(const f32x4*)(wa + (size_t)o0 * RANK + j * 4);
#pragma unroll
        for (int row = 0; row < 2; ++row) {
            const f32x4 t03 = {acc[row][0], acc[row][1], acc[row][2], acc[row][3]};
            const f32x4 t47 = {acc[row][4], acc[row][5], acc[row][6], acc[row][7]};
            f32x4 ov;
            ov.x = dot4v(A[0], t03) + dot4v(A[1], t47);
            ov.y = dot4v(A[2], t03) + dot4v(A[3], t47);
            ov.z = dot4v(A[4], t03) + dot4v(A[5], t47);
            ov.w = dot4v(A[6], t03) + dot4v(A[7], t47);
            __builtin_nontemporal_store(ov, (f32x4*)(out + (m0 + row) * D + o0));
        }
    }
}

extern "C" void kernel_launch(void* const* d_in, const int* in_sizes, int n_in,
                              void* d_out, int out_size, void* d_ws, size_t ws_size,
                              hipStream_t stream) {
    const float* h   = (const float*)d_in[0];
    const float* wa1 = (const float*)d_in[1];
    const float* wb1 = (const float*)d_in[2];
    const float* wa2 = (const float*)d_in[3];
    const float* wb2 = (const float*)d_in[4];
    const int*   ts  = (const int*)d_in[5];
    float* out = (float*)d_out;

    const int rows = in_sizes[0] / D;  // 8192

    unsigned* hdr  = (unsigned*)d_ws;
    unsigned* gcnt = (unsigned*)((char*)d_ws + WS_HCNT_OFF);
    unsigned long long* gsum = (unsigned long long*)((char*)d_ws + WS_HSUM_OFF);

    hipLaunchKernelGGL(k_init, dim3(1), dim3(1024), 0, stream, (unsigned*)d_ws);
    hipLaunchKernelGGL(k_pass_max, dim3(256, 2), dim3(256), 0, stream,
                       wa1, wb1, wa2, wb2, hdr);
    hipLaunchKernelGGL(k_pass_hist, dim3(256, 2), dim3(256), 0, stream,
                       wa1, wb1, wa2, wb2, hdr, gcnt, gsum);
    hipLaunchKernelGGL(k_select, dim3(1), dim3(1024), 0, stream,
                       hdr, gcnt, gsum, ts);
    hipLaunchKernelGGL(k_fused, dim3(rows / 8), dim3(256), 0, stream,
                       h, wa1, wb1, wa2, wb2, hdr, out);
}

// Round 7
// 105.506 us; speedup vs baseline: 1.3364x; 1.3364x over previous
//
#include <hip/hip_runtime.h>
#include <stdint.h>

#define D 4096
#define RANK 8
#define ALPHA 1.5f
#define BETA 0.5f
#define SUM_TIMESTEPS 28000
#define K_TOP 64
#define NBINS 1024

typedef float f32x4 __attribute__((ext_vector_type(4)));

// ws layout (bytes):
//   [0, 256)          : u32 hdr[]: [0]=maxbits1 [1]=maxbits2 [4]=flag
//   [256, 256+8K)     : u32 gcnt[2][NBINS]
//   [8448, 8448+16K)  : u64 gsum[2][NBINS]   (fixed-point, deterministic)
#define WS_HCNT_OFF 256
#define WS_HSUM_OFF (256 + 2 * NBINS * 4)
// words to zero: 64 + 2048 + 4096 = 6208
#define WS_ZERO_WORDS 6208

// fixed-point scale: 2^38 / max  (sum of 16.7M maximal values still < 2^62)
#define FIX_NUM 2.74877906944e11f
#define FIX_INV 3.637978807091713e-12   // 2^-38

__global__ __launch_bounds__(1024) void k_init(unsigned* __restrict__ w) {
    for (int i = threadIdx.x; i < WS_ZERO_WORDS; i += 1024) w[i] = 0u;
}

__device__ __forceinline__ float dot4v(f32x4 a, f32x4 b) {
    return fmaf(a.x, b.x, fmaf(a.y, b.y, fmaf(a.z, b.z, a.w * b.w)));
}

// ---------------------------------------------------------------------------
// Pass 1: global max of |wa@wb| per matrix (bitwise atomicMax: deterministic).
// ---------------------------------------------------------------------------
__global__ __launch_bounds__(256) void k_pass_max(
    const float* __restrict__ wa1, const float* __restrict__ wb1,
    const float* __restrict__ wa2, const float* __restrict__ wb2,
    unsigned* __restrict__ hdr) {
    const int tid = threadIdx.x;
    const int mat = blockIdx.y;
    const float* __restrict__ wa = mat ? wa2 : wa1;
    const float* __restrict__ wb = mat ? wb2 : wb1;
    const int i0 = (blockIdx.x & 3) * 1024 + tid * 4;
    const int obase = (blockIdx.x >> 2) * 64;

    f32x4 wbv[RANK];
#pragma unroll
    for (int r = 0; r < RANK; ++r)
        wbv[r] = *(const f32x4*)(wb + r * D + i0);

    float vmax = 0.f;
#pragma unroll 4
    for (int oo = 0; oo < 64; ++oo) {
        const float* __restrict__ war = wa + (size_t)(obase + oo) * RANK;
        f32x4 s = {0.f, 0.f, 0.f, 0.f};
#pragma unroll
        for (int r = 0; r < RANK; ++r) {
            const float a = war[r];
            s.x = fmaf(a, wbv[r].x, s.x);
            s.y = fmaf(a, wbv[r].y, s.y);
            s.z = fmaf(a, wbv[r].z, s.z);
            s.w = fmaf(a, wbv[r].w, s.w);
        }
        vmax = fmaxf(vmax, fmaxf(fmaxf(fabsf(s.x), fabsf(s.y)),
                                 fmaxf(fabsf(s.z), fabsf(s.w))));
    }
    for (int off = 32; off; off >>= 1)
        vmax = fmaxf(vmax, __shfl_xor(vmax, off, 64));
    __shared__ float smax[4];
    const int wave = tid >> 6, lane = tid & 63;
    if (lane == 0) smax[wave] = vmax;
    __syncthreads();
    if (tid == 0) {
        float m = fmaxf(fmaxf(smax[0], smax[1]), fmaxf(smax[2], smax[3]));
        atomicMax(&hdr[mat], __float_as_uint(m));  // positive floats: bit order == value order
    }
}

// ---------------------------------------------------------------------------
// Pass 2: histogram all |elem| >= 0.5*max. Counts = u32; sums = u64 FIXED
// POINT (av * 2^38/max) -> integer atomics are order-independent, so the
// whole flag path is bit-deterministic across replays.
// ---------------------------------------------------------------------------
__global__ __launch_bounds__(256) void k_pass_hist(
    const float* __restrict__ wa1, const float* __restrict__ wb1,
    const float* __restrict__ wa2, const float* __restrict__ wb2,
    const unsigned* __restrict__ hdr,
    unsigned* __restrict__ gcnt, unsigned long long* __restrict__ gsum) {
    __shared__ unsigned lcnt[NBINS];
    __shared__ unsigned long long lsum[NBINS];
    const int tid = threadIdx.x;
    const int mat = blockIdx.y;
    for (int b = tid; b < NBINS; b += 256) { lcnt[b] = 0u; lsum[b] = 0ull; }
    __syncthreads();

    const float* __restrict__ wa = mat ? wa2 : wa1;
    const float* __restrict__ wb = mat ? wb2 : wb1;
    const float M = __uint_as_float(hdr[mat]);
    const float T = 0.5f * M;
    const float fix = FIX_NUM / M;
    const unsigned bitsT = __float_as_uint(T);
    const int i0 = (blockIdx.x & 3) * 1024 + tid * 4;
    const int obase = (blockIdx.x >> 2) * 64;

    f32x4 wbv[RANK];
#pragma unroll
    for (int r = 0; r < RANK; ++r)
        wbv[r] = *(const f32x4*)(wb + r * D + i0);

#pragma unroll 2
    for (int oo = 0; oo < 64; ++oo) {
        const float* __restrict__ war = wa + (size_t)(obase + oo) * RANK;
        f32x4 s = {0.f, 0.f, 0.f, 0.f};
#pragma unroll
        for (int r = 0; r < RANK; ++r) {
            const float a = war[r];
            s.x = fmaf(a, wbv[r].x, s.x);
            s.y = fmaf(a, wbv[r].y, s.y);
            s.z = fmaf(a, wbv[r].z, s.z);
            s.w = fmaf(a, wbv[r].w, s.w);
        }
        const float av[4] = {fabsf(s.x), fabsf(s.y), fabsf(s.z), fabsf(s.w)};
#pragma unroll
        for (int j = 0; j < 4; ++j) {
            if (av[j] >= T) {
                unsigned k = (__float_as_uint(av[j]) - bitsT) >> 13;
                if (k > NBINS - 1u) k = NBINS - 1u;
                atomicAdd(&lcnt[k], 1u);
                atomicAdd(&lsum[k], (unsigned long long)(av[j] * fix));
            }
        }
    }
    __syncthreads();
    unsigned* __restrict__ gc = gcnt + (size_t)mat * NBINS;
    unsigned long long* __restrict__ gs = gsum + (size_t)mat * NBINS;
    for (int b = tid; b < NBINS; b += 256) {
        unsigned c = lcnt[b];
        if (c) {
            atomicAdd(&gc[b], c);
            atomicAdd(&gs[b], lsum[b]);
        }
    }
}

// ---------------------------------------------------------------------------
// Pass 3: one block, 1024 threads; suffix-scan histogram (integer — exact),
// top-64 cutoff, flag. Fully deterministic.
// ---------------------------------------------------------------------------
__global__ __launch_bounds__(1024) void k_select(
    unsigned* __restrict__ hdr,
    const unsigned* __restrict__ gcnt, const unsigned long long* __restrict__ gsum,
    const int* __restrict__ tsp) {
    __shared__ unsigned sc[NBINS];
    __shared__ unsigned long long ss[NBINS];
    __shared__ float res[2];
    __shared__ int sB;
    const int b = threadIdx.x;

    for (int mat = 0; mat < 2; ++mat) {
        if (b == 0) sB = -1;
        const unsigned c0 = gcnt[(size_t)mat * NBINS + b];
        const unsigned long long s0 = gsum[(size_t)mat * NBINS + b];
        __syncthreads();           // previous iteration's readers done
        sc[b] = c0;
        ss[b] = s0;
        __syncthreads();
        // Hillis-Steele suffix scan (integer adds: exact, order-independent)
        for (int step = 1; step < NBINS; step <<= 1) {
            unsigned c2 = 0u; unsigned long long s2 = 0ull;
            if (b + step < NBINS) { c2 = sc[b + step]; s2 = ss[b + step]; }
            __syncthreads();
            sc[b] += c2;
            ss[b] += s2;
            __syncthreads();
        }
        if (sc[b] >= K_TOP && (b == NBINS - 1 || sc[b + 1] < K_TOP)) sB = b;
        __syncthreads();
        if (b == 0) {
            const float M = __uint_as_float(hdr[mat]);
            const double inv = (double)M * FIX_INV;  // decode: units -> value
            float total;
            if (sB < 0) {
                total = (float)((double)ss[0] * inv);
            } else {
                const int B = sB;
                const unsigned cAbove = (B + 1 < NBINS) ? sc[B + 1] : 0u;
                const unsigned long long sAbove = (B + 1 < NBINS) ? ss[B + 1] : 0ull;
                const unsigned cb = sc[B] - cAbove;
                const unsigned long long sb = ss[B] - sAbove;
                const unsigned need = K_TOP - cAbove;
                total = (float)((double)sAbove * inv)
                      + (float)((double)sb * inv) * ((float)need / (float)cb);
            }
            res[mat] = total;
        }
        __syncthreads();
    }
    if (b == 0) {
        const int tr = (*tsp) % SUM_TIMESTEPS;
        const float scale = fmodf(ALPHA * (float)tr / (float)SUM_TIMESTEPS + BETA, ALPHA);
        const float temp_ratio = res[0] / (res[1] * scale);  // AVG_RATIO = 1.0
        hdr[4] = (temp_ratio > 1.0f) ? 1u : 0u;              // 1 -> matrix1
    }
}

// ---------------------------------------------------------------------------
// Fused GEMM, weight-stationary: block = 512 thr (8 waves), 16 rows/block,
// grid = 512 (2 blocks/CU, 16 waves/CU).
//   stage:   wb staged to LDS in two 64 KB halves (read ONCE per block from
//            L2 -> wb L2 traffic 512 MB -> 64 MB vs round 4/6).
//   phase 1: wave owns 2 rows; per k-step: 2 coalesced h loads (each h byte
//            read exactly once chip-wide) + 8 LDS reads + 64 FMA.
//   reduce:  96-shuffle butterfly -> lane0 writes t[16][8] to LDS (512 B).
//   phase 2: wave owns 512 out-cols (wa read once per block = 128 KB);
//            streams 16 rows x 512 cols of nontemporal stores.
// Both phases sit on compulsory traffic: ~134 MB read + ~134 MB write.
// ---------------------------------------------------------------------------
__global__ __launch_bounds__(512) void k_fused(
    const float* __restrict__ h,
    const float* __restrict__ wa1, const float* __restrict__ wb1,
    const float* __restrict__ wa2, const float* __restrict__ wb2,
    const unsigned* __restrict__ hdr,
    float* __restrict__ out) {
    const int tid = threadIdx.x;
    const int wave = tid >> 6, lane = tid & 63;
    const unsigned flag = hdr[4];
    const float* __restrict__ wa = flag ? wa1 : wa2;
    const float* __restrict__ wb = flag ? wb1 : wb2;
    const size_t m0 = (size_t)blockIdx.x * 16;
    const int r0 = wave * 2;  // this wave's 2 local rows

    __shared__ float wbs[RANK][2048];  // 64 KB: half of wb
    __shared__ float ts[16][8];        // final t for the block's 16 rows

    float acc[2][RANK];
#pragma unroll
    for (int row = 0; row < 2; ++row)
#pragma unroll
        for (int r = 0; r < RANK; ++r) acc[row][r] = 0.f;

    for (int hh = 0; hh < 2; ++hh) {
        __syncthreads();  // wbs readers from previous half are done
        // stage half of wb: [8][2048] f32 = 4096 f32x4, 512 threads -> 8 each
        {
            const f32x4* __restrict__ src = (const f32x4*)wb;
            f32x4* __restrict__ dst = (f32x4*)wbs;
#pragma unroll
            for (int q = 0; q < 8; ++q) {
                const int j = q * 512 + tid;       // [0, 4096)
                const int r = j >> 9;              // j / 512
                const int c4 = j & 511;            // f32x4 col within half
                dst[j] = src[r * 1024 + hh * 512 + c4];
            }
        }
        __syncthreads();
#pragma unroll 4
        for (int k = 0; k < 8; ++k) {
            const int il = k * 256 + lane * 4;
            f32x4 wbv[RANK];
#pragma unroll
            for (int r = 0; r < RANK; ++r)
                wbv[r] = *(const f32x4*)&wbs[r][il];
            f32x4 hv[2];
#pragma unroll
            for (int row = 0; row < 2; ++row)
                hv[row] = *(const f32x4*)(h + (m0 + r0 + row) * D + hh * 2048 + il);
#pragma unroll
            for (int row = 0; row < 2; ++row)
#pragma unroll
                for (int r = 0; r < RANK; ++r)
                    acc[row][r] = fmaf(hv[row].x, wbv[r].x,
                                  fmaf(hv[row].y, wbv[r].y,
                                  fmaf(hv[row].z, wbv[r].z,
                                  fmaf(hv[row].w, wbv[r].w, acc[row][r]))));
        }
    }

    // butterfly reduce over lanes -> all lanes hold t[row][r]
#pragma unroll
    for (int row = 0; row < 2; ++row)
#pragma unroll
        for (int r = 0; r < RANK; ++r)
#pragma unroll
            for (int off = 32; off; off >>= 1)
                acc[row][r] += __shfl_xor(acc[row][r], off, 64);
    if (lane == 0) {
#pragma unroll
        for (int row = 0; row < 2; ++row)
#pragma unroll
            for (int r = 0; r < RANK; ++r)
                ts[r0 + row][r] = acc[row][r];
    }
    __syncthreads();

    // phase 2: wave owns cols [wave*512, wave*512+512), 2 chunks of 256
#pragma unroll
    for (int cc = 0; cc < 2; ++cc) {
        const int o0 = wave * 512 + cc * 256 + lane * 4;
        f32x4 A[8];  // A[2j]: col (o0+j) r0..3, A[2j+1]: r4..7
#pragma unroll
        for (int j = 0; j < 8; ++j)
            A[j] = *(const f32x4*)(wa + (size_t)o0 * RANK + j * 4);
#pragma unroll 4
        for (int row = 0; row < 16; ++row) {
            const f32x4 t03 = *(const f32x4*)&ts[row][0];
            const f32x4 t47 = *(const f32x4*)&ts[row][4];
            f32x4 ov;
            ov.x = dot4v(A[0], t03) + dot4v(A[1], t47);
            ov.y = dot4v(A[2], t03) + dot4v(A[3], t47);
            ov.z = dot4v(A[4], t03) + dot4v(A[5], t47);
            ov.w = dot4v(A[6], t03) + dot4v(A[7], t47);
            __builtin_nontemporal_store(ov, (f32x4*)(out + (m0 + row) * D + o0));
        }
    }
}

extern "C" void kernel_launch(void* const* d_in, const int* in_sizes, int n_in,
                              void* d_out, int out_size, void* d_ws, size_t ws_size,
                              hipStream_t stream) {
    const float* h   = (const float*)d_in[0];
    const float* wa1 = (const float*)d_in[1];
    const float* wb1 = (const float*)d_in[2];
    const float* wa2 = (const float*)d_in[3];
    const float* wb2 = (const float*)d_in[4];
    const int*   ts  = (const int*)d_in[5];
    float* out = (float*)d_out;

    const int rows = in_sizes[0] / D;  // 8192

    unsigned* hdr  = (unsigned*)d_ws;
    unsigned* gcnt = (unsigned*)((char*)d_ws + WS_HCNT_OFF);
    unsigned long long* gsum = (unsigned long long*)((char*)d_ws + WS_HSUM_OFF);

    hipLaunchKernelGGL(k_init, dim3(1), dim3(1024), 0, stream, (unsigned*)d_ws);
    hipLaunchKernelGGL(k_pass_max, dim3(256, 2), dim3(256), 0, stream,
                       wa1, wb1, wa2, wb2, hdr);
    hipLaunchKernelGGL(k_pass_hist, dim3(256, 2), dim3(256), 0, stream,
                       wa1, wb1, wa2, wb2, hdr, gcnt, gsum);
    hipLaunchKernelGGL(k_select, dim3(1), dim3(1024), 0, stream,
                       hdr, gcnt, gsum, ts);
    hipLaunchKernelGGL(k_fused, dim3(rows / 16), dim3(512), 0, stream,
                       h, wa1, wb1, wa2, wb2, hdr, out);
}